// Round 13
// baseline (214.357 us; speedup 1.0000x reference)
//
#include <hip/hip_runtime.h>
#include <hip/hip_bf16.h>
#include <stdint.h>

typedef __bf16 v8bf __attribute__((ext_vector_type(8)));
typedef float  v16f __attribute__((ext_vector_type(16)));
typedef unsigned short u16;

#define NTOK 16384
#define KDIM 1024

__device__ __forceinline__ u16 f2bf(float f) {
  uint32_t b = __builtin_bit_cast(uint32_t, f);
  b += 0x7FFFu + ((b >> 16) & 1u);
  return (u16)(b >> 16);
}

__device__ __forceinline__ void gl_lds16(const u16* g, u16* l) {
  __builtin_amdgcn_global_load_lds(
      (const __attribute__((address_space(1))) uint32_t*)g,
      (__attribute__((address_space(3))) uint32_t*)l,
      16, 0, 0);
}

__device__ __forceinline__ void bar() {
  __builtin_amdgcn_sched_barrier(0);
  __builtin_amdgcn_s_barrier();
  __builtin_amdgcn_sched_barrier(0);
}
#define LGKM0() do { asm volatile("s_waitcnt lgkmcnt(0)" ::: "memory"); \
                     __builtin_amdgcn_sched_barrier(0); } while (0)
#define VMW(n)  do { asm volatile("s_waitcnt vmcnt(" #n ")" ::: "memory"); \
                     __builtin_amdgcn_sched_barrier(0); } while (0)

// ---------------- fused fp32 -> bf16 convert for all three tensors -----
__global__ void cvt_all(const float* __restrict__ x, const float* __restrict__ wq,
                        const float* __restrict__ wp, u16* __restrict__ xo,
                        u16* __restrict__ wqo, u16* __restrict__ wpo) {
  size_t id = (size_t)blockIdx.x * 256 + threadIdx.x;
  const float* src; u16* dst;
  if (id < 2097152)      { src = x  + id * 8;              dst = xo  + id * 8; }
  else if (id < 2490368) { src = wq + (id - 2097152) * 8;  dst = wqo + (id - 2097152) * 8; }
  else                   { src = wp + (id - 2490368) * 8;  dst = wpo + (id - 2490368) * 8; }
  float4 a = *(const float4*)(src);
  float4 b = *(const float4*)(src + 4);
  union { u16 u[8]; uint4 v; } pk;
  pk.u[0]=f2bf(a.x); pk.u[1]=f2bf(a.y); pk.u[2]=f2bf(a.z); pk.u[3]=f2bf(a.w);
  pk.u[4]=f2bf(b.x); pk.u[5]=f2bf(b.y); pk.u[6]=f2bf(b.z); pk.u[7]=f2bf(b.w);
  *(uint4*)(dst) = pk.v;
}

// ---------------- C = A * B^T + bias ; 256x256 tile, BK=64 -------------
// v13 = v10 skeleton EXACTLY (2 bufs x {A-lo,A-hi,B-lo,B-hi} 16KB halves,
// 4 phases/K-tile, in-place t+2 staging, VMW(0)@P1, persistent rounds,
// supertile XCD map, row&7 chunk-XOR swizzle) with 32x32x16 MFMA:
//   per-wave C = 128x64 = 4(m) x 2(n) tiles of 32x32, acc[4][2] f32x16.
//   A-op: row=lane&31, k=(lane>>5)*8+e per 16-k step s (chunk 2s+hi).
//   C/D (m74/m101): col=lane&31, row=(rg&3)+8*(rg>>2)+4*(lane>>5).
// Phases: P0 Q(m01,n0); P1 Q(m01,n1)+rd A-hi(t); P2 Q(m23,n1)+rd B1(t+1);
//         P3 Q(m23,n0)+rd A-lo,B0(t+1). Stage/wait ledger = v10 verbatim.
template<int NTOT, bool OUT_BF16, int ROUNDS>
__global__ __launch_bounds__(512, 2)
void gemm_bt(const u16* __restrict__ A, const u16* __restrict__ Bw,
             const float* __restrict__ bias, void* __restrict__ out) {
  const int bid = blockIdx.x;
  const int xcd = bid & 7, loc = bid >> 3;

  extern __shared__ __align__(16) u16 smem[];  // 2 x 32768 elems = 128 KiB

  const int tid = threadIdx.x, lane = tid & 63, w = tid >> 6;
  const int wr = w >> 2, wc = w & 3;
  const int l31 = lane & 31, hi = lane >> 5, l7 = lane & 7;

  v16f acc[4][2];
#pragma unroll
  for (int i = 0; i < 4; ++i)
#pragma unroll
    for (int j = 0; j < 2; ++j)
#pragma unroll
      for (int e = 0; e < 16; ++e) acc[i][j][e] = 0.f;

  // staging geometry (source-side swizzle; LDS dest linear) — v10 verbatim
  const int srow = tid >> 3;
  const int sc   = (tid & 7) ^ (srow & 7);
  const size_t soff = (size_t)srow * KDIM + (size_t)sc * 8;
  const u16* Ab; const u16* Bb; int bm, bn;
  auto setbase = [&](int r) {
    int q = r * 32 + loc;
    bm = xcd * 8 + (q & 7);
    bn = q >> 3;
    Ab = A  + (size_t)bm * 256 * KDIM;
    Bb = Bw + (size_t)bn * 256 * KDIM;
  };
  auto stageH = [&](int dstoff, const u16* src) {
    gl_lds16(src + soff, smem + dstoff + (size_t)tid * 8);
    gl_lds16(src + soff + (size_t)64 * KDIM, smem + dstoff + (size_t)tid * 8 + 4096);
  };
  auto prolog = [&]() {   // tiles 0 (buf0) then 1 (buf1): 16 loads
    stageH(0,     Ab);
    stageH(8192,  Ab + (size_t)128 * KDIM);
    stageH(16384, Bb);
    stageH(24576, Bb + (size_t)128 * KDIM);
    stageH(32768 + 16384, Bb + 64);
    stageH(32768 + 24576, Bb + (size_t)128 * KDIM + 64);
    stageH(32768 + 0,     Ab + 64);
    stageH(32768 + 8192,  Ab + (size_t)128 * KDIM + 64);
  };

  // frag bases; swizzled chunk for 16-k step s: phys=(2s+hi)^(row&7), row&7==l7
  const int ha = wr * 8192 + l31 * 64;                     // + mrow*... below
  const int hb = 16384 + (wc >> 1) * 8192 + ((wc & 1) * 64 + l31) * 64;
#define CK(S) ((((S) * 2 + hi) ^ l7) << 3)

  v8bf Alo[2][4], Ahi[2][4], B0f[4], B1f[4];

#define RD_A(BUF, ROFF, DEST) do {                                            \
  _Pragma("unroll") for (int mm = 0; mm < 2; ++mm)                            \
  _Pragma("unroll") for (int s = 0; s < 4; ++s)                               \
    DEST[mm][s] = *(const v8bf*)(smem + (BUF) + ha                            \
                  + ((ROFF) + mm * 32) * 64 + CK(s));                         \
} while (0)
#define RD_B(BUF, N, DEST) do {                                               \
  _Pragma("unroll") for (int s = 0; s < 4; ++s)                               \
    DEST[s] = *(const v8bf*)(smem + (BUF) + hb + (N) * 32 * 64 + CK(s));      \
} while (0)
#define MM8(P, N, AF, BF) do {                                                \
  __builtin_amdgcn_s_setprio(1);                                              \
  _Pragma("unroll") for (int s = 0; s < 4; ++s)                               \
  _Pragma("unroll") for (int mm = 0; mm < 2; ++mm)                            \
    acc[(P)*2+mm][N] = __builtin_amdgcn_mfma_f32_32x32x16_bf16(               \
        AF[mm][s], BF[s], acc[(P)*2+mm][N], 0, 0, 0);                         \
  __builtin_amdgcn_s_setprio(0);                                              \
} while (0)

#define TILE(T, D, DN, ST, PR) do {                                           \
  /* P0 */                                                                    \
  LGKM0(); MM8(0, 0, Alo, B0f); bar();                                        \
  /* P1 */                                                                    \
  VMW(0);                                                                     \
  if (ST) stageH((D) + 16384, Bb + (size_t)((T)+2) * 64);                     \
  LGKM0(); MM8(0, 1, Alo, B1f);                                               \
  RD_A((D), 64, Ahi);                                                         \
  bar();                                                                      \
  /* P2 */                                                                    \
  if (ST) stageH((D) + 24576, Bb + (size_t)128*KDIM + (size_t)((T)+2) * 64);  \
  LGKM0(); MM8(1, 1, Ahi, B1f);                                               \
  if (PR) RD_B((DN), 1, B1f);                                                 \
  bar();                                                                      \
  /* P3 */                                                                    \
  if (ST) { stageH((D) + 0,    Ab + (size_t)((T)+2) * 64);                    \
            stageH((D) + 8192, Ab + (size_t)128*KDIM + (size_t)((T)+2)*64); } \
  LGKM0(); MM8(1, 0, Ahi, B0f);                                               \
  if (PR) { RD_A((DN), 0, Alo); RD_B((DN), 0, B0f); }                         \
  bar();                                                                      \
} while (0)

  // initial prologue (round 0): VMW(8) forces tile0's 8, leaves tile1's 8.
  setbase(0);
  prolog();
  VMW(8);
  bar();
  RD_A(0, 0, Alo);
  RD_B(0, 0, B0f);
  RD_B(0, 1, B1f);

  for (int r = 0; r < ROUNDS; ++r) {
    for (int j = 0; j < 7; ++j) {
      TILE(2 * j,     0,     32768, 1, 1);
      TILE(2 * j + 1, 32768, 0,     1, 1);
    }
    TILE(14, 0,     32768, 0, 1);
    TILE(15, 32768, 0,     0, 0);

    const int bmw = bm, bnw = bn;
    if (r + 1 < ROUNDS) { setbase(r + 1); prolog(); }   // loads first

    // C-write (stores issue under the prologue loads); 32x32 C/D mapping
    {
      const int col0 = bnw * 256 + wc * 64 + l31;
      const int row0 = bmw * 256 + wr * 128 + 4 * hi;
#pragma unroll
      for (int m = 0; m < 4; ++m) {
#pragma unroll
        for (int n = 0; n < 2; ++n) {
          const int gc = col0 + n * 32;
          const float bv = bias[gc];
#pragma unroll
          for (int rg = 0; rg < 16; ++rg) {
            const int grow = row0 + m * 32 + (rg & 3) + 8 * (rg >> 2);
            const size_t idx = (size_t)grow * NTOT + gc;
            const float v = acc[m][n][rg] + bv;
            if constexpr (OUT_BF16) ((u16*)out)[idx] = f2bf(v);
            else                    ((float*)out)[idx] = v;
          }
        }
      }
    }

    if (r + 1 < ROUNDS) {
#pragma unroll
      for (int i = 0; i < 4; ++i)
#pragma unroll
        for (int j = 0; j < 2; ++j)
#pragma unroll
          for (int e = 0; e < 16; ++e) acc[i][j][e] = 0.f;
      VMW(0);          // drain prologue loads (stores ack early at L2)
      bar();
      RD_A(0, 0, Alo);
      RD_B(0, 0, B0f);
      RD_B(0, 1, B1f);
    }
  }
#undef TILE
#undef MM8
#undef RD_A
#undef RD_B
#undef CK
}

// ---------------- per-token head-mix attention -------------------------
__global__ __launch_bounds__(256)
void attn_mix(const u16* __restrict__ qkv, u16* __restrict__ outp) {
  __shared__ __align__(16) u16 sq[4][3072];
  __shared__ float sp[4][16][16];
  const int tid = threadIdx.x, lane = tid & 63, w = tid >> 6;
  const size_t tok = (size_t)blockIdx.x * 4 + w;
  const u16* src = qkv + tok * 3072;
#pragma unroll
  for (int i = 0; i < 6; ++i) {
    int t = i * 64 + lane;
    int row = t >> 3;
    int c = (t & 7) ^ (row & 7);
    gl_lds16(src + row * 64 + c * 8, &sq[w][t * 8]);
  }
  __syncthreads();

  const int h = lane >> 2, gb = lane & 3;
  v8bf qv[8];
#pragma unroll
  for (int c = 0; c < 8; ++c)
    qv[c] = *(const v8bf*)&sq[w][h * 64 + ((c ^ (h & 7)) * 8)];

  float s[4];
#pragma unroll
  for (int g4 = 0; g4 < 4; ++g4) {
    const int g = gb * 4 + g4;
    float a = 0.f;
#pragma unroll
    for (int c = 0; c < 8; ++c) {
      v8bf kv = *(const v8bf*)&sq[w][1024 + g * 64 + ((c ^ (g & 7)) * 8)];
#pragma unroll
      for (int j = 0; j < 8; ++j) a += (float)qv[c][j] * (float)kv[j];
    }
    s[g4] = a * 0.125f;
  }
  float m = fmaxf(fmaxf(s[0], s[1]), fmaxf(s[2], s[3]));
  m = fmaxf(m, __shfl_xor(m, 1));
  m = fmaxf(m, __shfl_xor(m, 2));
  float p[4], sum = 0.f;
#pragma unroll
  for (int g4 = 0; g4 < 4; ++g4) { p[g4] = __expf(s[g4] - m); sum += p[g4]; }
  sum += __shfl_xor(sum, 1);
  sum += __shfl_xor(sum, 2);
  const float inv = 1.f / sum;
#pragma unroll
  for (int g4 = 0; g4 < 4; ++g4) sp[w][h][gb * 4 + g4] = p[g4] * inv;
  __syncthreads();

  float o[16];
#pragma unroll
  for (int j = 0; j < 16; ++j) o[j] = 0.f;
  const int db = gb;
#pragma unroll
  for (int g = 0; g < 16; ++g) {
    const float a = sp[w][h][g];
    v8bf v0 = *(const v8bf*)&sq[w][2048 + g * 64 + (((db * 2)     ^ (g & 7)) * 8)];
    v8bf v1 = *(const v8bf*)&sq[w][2048 + g * 64 + (((db * 2 + 1) ^ (g & 7)) * 8)];
#pragma unroll
    for (int j = 0; j < 8; ++j) { o[j] += a * (float)v0[j]; o[8 + j] += a * (float)v1[j]; }
  }
  union { u16 u[16]; uint4 v[2]; } ob;
#pragma unroll
  for (int j = 0; j < 16; ++j) ob.u[j] = f2bf(o[j]);
  u16* dst = outp + tok * 1024 + h * 64 + db * 16;
  *(uint4*)dst = ob.v[0];
  *((uint4*)dst + 1) = ob.v[1];
}

extern "C" void kernel_launch(void* const* d_in, const int* in_sizes, int n_in,
                              void* d_out, int out_size, void* d_ws, size_t ws_size,
                              hipStream_t stream) {
  const float* x      = (const float*)d_in[0];
  const float* w_qkv  = (const float*)d_in[1];
  const float* b_qkv  = (const float*)d_in[2];
  const float* w_proj = (const float*)d_in[3];
  const float* b_proj = (const float*)d_in[4];

  char* ws = (char*)d_ws;
  u16* x_bf    = (u16*)(ws);
  u16* wqkv_bf = (u16*)(ws + (size_t)33554432);
  u16* wp_bf   = (u16*)(ws + (size_t)39845888);
  u16* qkv_bf  = (u16*)(ws + (size_t)41943040);
  u16* at_bf   = (u16*)(ws + (size_t)142606336);

  (void)hipFuncSetAttribute((const void*)&gemm_bt<3072, true, 3>,
                            hipFuncAttributeMaxDynamicSharedMemorySize, 131072);
  (void)hipFuncSetAttribute((const void*)&gemm_bt<1024, false, 1>,
                            hipFuncAttributeMaxDynamicSharedMemorySize, 131072);

  cvt_all<<<dim3(10240), dim3(256), 0, stream>>>(x, w_qkv, w_proj,
                                                 x_bf, wqkv_bf, wp_bf);

  gemm_bt<3072, true, 3><<<dim3(256), dim3(512), 131072, stream>>>(x_bf, wqkv_bf, b_qkv, qkv_bf);
  attn_mix<<<dim3(4096), dim3(256), 0, stream>>>(qkv_bf, at_bf);
  gemm_bt<1024, false, 1><<<dim3(256), dim3(512), 131072, stream>>>(at_bf, wp_bf, b_proj, d_out);
}

// Round 14
// 199.335 us; speedup vs baseline: 1.0754x; 1.0754x over previous
//
#include <hip/hip_runtime.h>
#include <hip/hip_bf16.h>
#include <stdint.h>

typedef __bf16 v8bf __attribute__((ext_vector_type(8)));
typedef float  v4f  __attribute__((ext_vector_type(4)));
typedef unsigned short u16;

#define NTOK 16384
#define KDIM 1024

__device__ __forceinline__ u16 f2bf(float f) {
  uint32_t b = __builtin_bit_cast(uint32_t, f);
  b += 0x7FFFu + ((b >> 16) & 1u);
  return (u16)(b >> 16);
}

__device__ __forceinline__ void gl_lds16(const u16* g, u16* l) {
  __builtin_amdgcn_global_load_lds(
      (const __attribute__((address_space(1))) uint32_t*)g,
      (__attribute__((address_space(3))) uint32_t*)l,
      16, 0, 0);
}

__device__ __forceinline__ void bar() {
  __builtin_amdgcn_sched_barrier(0);
  __builtin_amdgcn_s_barrier();
  __builtin_amdgcn_sched_barrier(0);
}
#define LGKM0() do { asm volatile("s_waitcnt lgkmcnt(0)" ::: "memory"); \
                     __builtin_amdgcn_sched_barrier(0); } while (0)
#define VMW(n)  do { asm volatile("s_waitcnt vmcnt(" #n ")" ::: "memory"); \
                     __builtin_amdgcn_sched_barrier(0); } while (0)

// ---------------- fused fp32 -> bf16 convert for all three tensors -----
__global__ void cvt_all(const float* __restrict__ x, const float* __restrict__ wq,
                        const float* __restrict__ wp, u16* __restrict__ xo,
                        u16* __restrict__ wqo, u16* __restrict__ wpo) {
  size_t id = (size_t)blockIdx.x * 256 + threadIdx.x;
  const float* src; u16* dst;
  if (id < 2097152)      { src = x  + id * 8;              dst = xo  + id * 8; }
  else if (id < 2490368) { src = wq + (id - 2097152) * 8;  dst = wqo + (id - 2097152) * 8; }
  else                   { src = wp + (id - 2490368) * 8;  dst = wpo + (id - 2490368) * 8; }
  float4 a = *(const float4*)(src);
  float4 b = *(const float4*)(src + 4);
  union { u16 u[8]; uint4 v; } pk;
  pk.u[0]=f2bf(a.x); pk.u[1]=f2bf(a.y); pk.u[2]=f2bf(a.z); pk.u[3]=f2bf(a.w);
  pk.u[4]=f2bf(b.x); pk.u[5]=f2bf(b.y); pk.u[6]=f2bf(b.z); pk.u[7]=f2bf(b.w);
  *(uint4*)(dst) = pk.v;
}

// ---------------- C = A * B^T + bias ; 256x256 tile, BK=64 -------------
// v14 = v10 verbatim (best verified: GEMM1 995 TF) with one micro-fix:
// round-boundary drain VMW(0) -> VMW(8) (tile-0's 8 prologue loads forced,
// tile-1's 8 left in flight — identical ledger to the initial prologue).
// Structure: 2 bufs x {A-lo,A-hi,B-lo,B-hi} 16KB halves, 4 phases/K-tile,
// cross-phase post-MFMA ds_reads, in-place t+2 staging, VMW(0)@P1,
// persistent ROUNDS + supertile XCD map, row&7 chunk-XOR swizzle.
template<int NTOT, bool OUT_BF16, int ROUNDS>
__global__ __launch_bounds__(512, 2)
void gemm_bt(const u16* __restrict__ A, const u16* __restrict__ Bw,
             const float* __restrict__ bias, void* __restrict__ out) {
  const int bid = blockIdx.x;
  const int xcd = bid & 7, loc = bid >> 3;

  extern __shared__ __align__(16) u16 smem[];  // 2 x 32768 elems = 128 KiB

  const int tid = threadIdx.x, lane = tid & 63, w = tid >> 6;
  const int wr = w >> 2, wc = w & 3;

  v4f acc[8][4];
#pragma unroll
  for (int i = 0; i < 8; ++i)
#pragma unroll
    for (int j = 0; j < 4; ++j) acc[i][j] = v4f{0.f, 0.f, 0.f, 0.f};

  // staging geometry (source-side swizzle; LDS dest linear)
  const int srow = tid >> 3;
  const int sc   = (tid & 7) ^ (srow & 7);
  const size_t soff = (size_t)srow * KDIM + (size_t)sc * 8;
  const u16* Ab; const u16* Bb; int bm, bn;
  auto setbase = [&](int r) {
    int q = r * 32 + loc;
    bm = xcd * 8 + (q & 7);
    bn = q >> 3;
    Ab = A  + (size_t)bm * 256 * KDIM;
    Bb = Bw + (size_t)bn * 256 * KDIM;
  };
  auto stageH = [&](int dstoff, const u16* src) {
    gl_lds16(src + soff, smem + dstoff + (size_t)tid * 8);
    gl_lds16(src + soff + (size_t)64 * KDIM, smem + dstoff + (size_t)tid * 8 + 4096);
  };
  auto prolog = [&]() {   // tiles 0 (buf0) then 1 (buf1): 16 loads
    stageH(0,     Ab);
    stageH(8192,  Ab + (size_t)128 * KDIM);
    stageH(16384, Bb);
    stageH(24576, Bb + (size_t)128 * KDIM);
    stageH(32768 + 16384, Bb + 64);
    stageH(32768 + 24576, Bb + (size_t)128 * KDIM + 64);
    stageH(32768 + 0,     Ab + 64);
    stageH(32768 + 8192,  Ab + (size_t)128 * KDIM + 64);
  };

  // frag reads: read-side swizzle folds to per-lane constants
  const int rA  = lane & 15;
  const int ck0 = (((lane >> 4) ^ (lane & 7)) << 3);
  const int ck1 = ((((lane >> 4) + 4) ^ (lane & 7)) << 3);
  const int ha = wr * 8192;
  const int hb = 16384 + (wc >> 1) * 8192 + (wc & 1) * 64 * 64;

  v8bf Af[4][2], B0r[2][2], B1r[2][2];

#define RD_A(BUF, ROFF) do {                                                  \
  _Pragma("unroll") for (int f = 0; f < 4; ++f) {                             \
    Af[f][0] = *(const v8bf*)(smem + (BUF) + ha + ((ROFF)+f*16+rA)*64 + ck0); \
    Af[f][1] = *(const v8bf*)(smem + (BUF) + ha + ((ROFF)+f*16+rA)*64 + ck1);}\
} while (0)
#define RD_B(BUF, REG, ROFF) do {                                             \
  _Pragma("unroll") for (int g = 0; g < 2; ++g) {                             \
    REG[g][0] = *(const v8bf*)(smem + (BUF) + hb + ((ROFF)+g*16+rA)*64 + ck0);\
    REG[g][1] = *(const v8bf*)(smem + (BUF) + hb + ((ROFF)+g*16+rA)*64 + ck1);}\
} while (0)
#define MM16(FI, GI, BF) do {                                                 \
  __builtin_amdgcn_s_setprio(1);                                              \
  _Pragma("unroll") for (int f = 0; f < 4; ++f)                               \
  _Pragma("unroll") for (int g = 0; g < 2; ++g) {                             \
    acc[(FI)+f][(GI)+g] = __builtin_amdgcn_mfma_f32_16x16x32_bf16(            \
        Af[f][0], BF[g][0], acc[(FI)+f][(GI)+g], 0, 0, 0);                    \
    acc[(FI)+f][(GI)+g] = __builtin_amdgcn_mfma_f32_16x16x32_bf16(            \
        Af[f][1], BF[g][1], acc[(FI)+f][(GI)+g], 0, 0, 0);                    \
  }                                                                           \
  __builtin_amdgcn_s_setprio(0);                                              \
} while (0)

#define TILE(T, D, DN, ST, PR) do {                                           \
  /* P0 */                                                                    \
  LGKM0(); MM16(0, 0, B0r); bar();                                            \
  /* P1 */                                                                    \
  VMW(0);                                                                     \
  if (ST) stageH((D) + 16384, Bb + (size_t)((T)+2) * 64);                     \
  LGKM0(); MM16(0, 2, B1r);                                                   \
  RD_A((D), 64);                                                              \
  bar();                                                                      \
  /* P2 */                                                                    \
  if (ST) stageH((D) + 24576, Bb + (size_t)128*KDIM + (size_t)((T)+2) * 64);  \
  LGKM0(); MM16(4, 2, B1r);                                                   \
  if (PR) RD_B((DN), B1r, 32);                                                \
  bar();                                                                      \
  /* P3 */                                                                    \
  if (ST) { stageH((D) + 0,    Ab + (size_t)((T)+2) * 64);                    \
            stageH((D) + 8192, Ab + (size_t)128*KDIM + (size_t)((T)+2)*64); } \
  LGKM0(); MM16(4, 0, B0r);                                                   \
  if (PR) { RD_A((DN), 0); RD_B((DN), B0r, 0); }                              \
  bar();                                                                      \
} while (0)

  // initial prologue (round 0): VMW(8) forces tile0's 8, leaves tile1's 8.
  setbase(0);
  prolog();
  VMW(8);
  bar();
  RD_A(0, 0);
  RD_B(0, B0r, 0);
  RD_B(0, B1r, 32);

  for (int r = 0; r < ROUNDS; ++r) {
    for (int j = 0; j < 7; ++j) {
      TILE(2 * j,     0,     32768, 1, 1);
      TILE(2 * j + 1, 32768, 0,     1, 1);
    }
    TILE(14, 0,     32768, 0, 1);
    TILE(15, 32768, 0,     0, 0);

    const int bmw = bm, bnw = bn;
    if (r + 1 < ROUNDS) { setbase(r + 1); prolog(); }   // loads first

    // C-write (stores issue under the prologue loads)
    {
      const int col0 = bnw * 256 + wc * 64 + (lane & 15);
      const int row0 = bmw * 256 + wr * 128 + ((lane >> 4) << 2);
#pragma unroll
      for (int mf = 0; mf < 8; ++mf) {
#pragma unroll
        for (int nf = 0; nf < 4; ++nf) {
          const int gc = col0 + nf * 16;
          const float bv = bias[gc];
#pragma unroll
          for (int j = 0; j < 4; ++j) {
            const size_t idx = (size_t)(row0 + mf * 16 + j) * NTOT + gc;
            const float v = acc[mf][nf][j] + bv;
            if constexpr (OUT_BF16) ((u16*)out)[idx] = f2bf(v);
            else                    ((float*)out)[idx] = v;
          }
        }
      }
    }

    if (r + 1 < ROUNDS) {
#pragma unroll
      for (int i = 0; i < 8; ++i)
#pragma unroll
        for (int j = 0; j < 4; ++j) acc[i][j] = v4f{0.f, 0.f, 0.f, 0.f};
      VMW(8);          // force tile-0's 8 loads; tile-1's 8 stay in flight
      bar();
      RD_A(0, 0);
      RD_B(0, B0r, 0);
      RD_B(0, B1r, 32);
    }
  }
#undef TILE
#undef MM16
#undef RD_A
#undef RD_B
}

// ---------------- per-token head-mix attention -------------------------
__global__ __launch_bounds__(256)
void attn_mix(const u16* __restrict__ qkv, u16* __restrict__ outp) {
  __shared__ __align__(16) u16 sq[4][3072];
  __shared__ float sp[4][16][16];
  const int tid = threadIdx.x, lane = tid & 63, w = tid >> 6;
  const size_t tok = (size_t)blockIdx.x * 4 + w;
  const u16* src = qkv + tok * 3072;
#pragma unroll
  for (int i = 0; i < 6; ++i) {
    int t = i * 64 + lane;
    int row = t >> 3;
    int c = (t & 7) ^ (row & 7);
    gl_lds16(src + row * 64 + c * 8, &sq[w][t * 8]);
  }
  __syncthreads();

  const int h = lane >> 2, gb = lane & 3;
  v8bf qv[8];
#pragma unroll
  for (int c = 0; c < 8; ++c)
    qv[c] = *(const v8bf*)&sq[w][h * 64 + ((c ^ (h & 7)) * 8)];

  float s[4];
#pragma unroll
  for (int g4 = 0; g4 < 4; ++g4) {
    const int g = gb * 4 + g4;
    float a = 0.f;
#pragma unroll
    for (int c = 0; c < 8; ++c) {
      v8bf kv = *(const v8bf*)&sq[w][1024 + g * 64 + ((c ^ (g & 7)) * 8)];
#pragma unroll
      for (int j = 0; j < 8; ++j) a += (float)qv[c][j] * (float)kv[j];
    }
    s[g4] = a * 0.125f;
  }
  float m = fmaxf(fmaxf(s[0], s[1]), fmaxf(s[2], s[3]));
  m = fmaxf(m, __shfl_xor(m, 1));
  m = fmaxf(m, __shfl_xor(m, 2));
  float p[4], sum = 0.f;
#pragma unroll
  for (int g4 = 0; g4 < 4; ++g4) { p[g4] = __expf(s[g4] - m); sum += p[g4]; }
  sum += __shfl_xor(sum, 1);
  sum += __shfl_xor(sum, 2);
  const float inv = 1.f / sum;
#pragma unroll
  for (int g4 = 0; g4 < 4; ++g4) sp[w][h][gb * 4 + g4] = p[g4] * inv;
  __syncthreads();

  float o[16];
#pragma unroll
  for (int j = 0; j < 16; ++j) o[j] = 0.f;
  const int db = gb;
#pragma unroll
  for (int g = 0; g < 16; ++g) {
    const float a = sp[w][h][g];
    v8bf v0 = *(const v8bf*)&sq[w][2048 + g * 64 + (((db * 2)     ^ (g & 7)) * 8)];
    v8bf v1 = *(const v8bf*)&sq[w][2048 + g * 64 + (((db * 2 + 1) ^ (g & 7)) * 8)];
#pragma unroll
    for (int j = 0; j < 8; ++j) { o[j] += a * (float)v0[j]; o[8 + j] += a * (float)v1[j]; }
  }
  union { u16 u[16]; uint4 v[2]; } ob;
#pragma unroll
  for (int j = 0; j < 16; ++j) ob.u[j] = f2bf(o[j]);
  u16* dst = outp + tok * 1024 + h * 64 + db * 16;
  *(uint4*)dst = ob.v[0];
  *((uint4*)dst + 1) = ob.v[1];
}

extern "C" void kernel_launch(void* const* d_in, const int* in_sizes, int n_in,
                              void* d_out, int out_size, void* d_ws, size_t ws_size,
                              hipStream_t stream) {
  const float* x      = (const float*)d_in[0];
  const float* w_qkv  = (const float*)d_in[1];
  const float* b_qkv  = (const float*)d_in[2];
  const float* w_proj = (const float*)d_in[3];
  const float* b_proj = (const float*)d_in[4];

  char* ws = (char*)d_ws;
  u16* x_bf    = (u16*)(ws);
  u16* wqkv_bf = (u16*)(ws + (size_t)33554432);
  u16* wp_bf   = (u16*)(ws + (size_t)39845888);
  u16* qkv_bf  = (u16*)(ws + (size_t)41943040);
  u16* at_bf   = (u16*)(ws + (size_t)142606336);

  (void)hipFuncSetAttribute((const void*)&gemm_bt<3072, true, 3>,
                            hipFuncAttributeMaxDynamicSharedMemorySize, 131072);
  (void)hipFuncSetAttribute((const void*)&gemm_bt<1024, false, 1>,
                            hipFuncAttributeMaxDynamicSharedMemorySize, 131072);

  cvt_all<<<dim3(10240), dim3(256), 0, stream>>>(x, w_qkv, w_proj,
                                                 x_bf, wqkv_bf, wp_bf);

  gemm_bt<3072, true, 3><<<dim3(256), dim3(512), 131072, stream>>>(x_bf, wqkv_bf, b_qkv, qkv_bf);
  attn_mix<<<dim3(4096), dim3(256), 0, stream>>>(qkv_bf, at_bf);
  gemm_bt<1024, false, 1><<<dim3(256), dim3(512), 131072, stream>>>(at_bf, wp_bf, b_proj, d_out);
}